// Round 4
// baseline (1151.325 us; speedup 1.0000x reference)
//
#include <hip/hip_runtime.h>
#include <hip/hip_bf16.h>

// ---------------------------------------------------------------------------
// QLenet forward, exact-math strategy (round-0 notes):
//   All fq() outputs are e5m2 grid values (<=3 significant bits). Products of
//   two grid values have <=6-bit mantissas; dot sums (<=400 terms, bounded
//   exponent span) are EXACT in f64 -> order-independent -> matches float64
//   numpy reference. Intermediates stored as bf16 (exact for grid values).
// Round 3 -> 4:
//   * fq_d rewritten: f64 division replaced by integer RNE bit-trick on the
//     mantissa (normal path) / rint * 2^16 (subnormal path). ~4x cheaper.
//   * kconv1 task = 14-wide half row: acc[14]+xv[18] -> ~90 live VGPRs
//     (was 192, 11% occupancy), __launch_bounds__(256,4).
//   * 8 prep launches merged into one kprep.
// ---------------------------------------------------------------------------

#define BATCH 8192

// fq: round to FP(e5m2) nearest-even, subnormal granule 2^-16, clip +-57344.
// Normal path (|x| >= 2^-14): integer round-to-nearest-even of the f64
// mantissa to 2 bits; carry propagates into the exponent automatically.
__device__ __forceinline__ double fq_d(double x) {
    long long b = __double_as_longlong(x);
    long long ab = b & 0x7fffffffffffffffLL;
    if (ab == 0) return x;                       // +-0 preserved (ref: where(ax>0,...))
    double q;
    if (ab >= 0x3F10000000000000LL) {            // |x| >= 2^-14
        long long r = b + 0x0001FFFFFFFFFFFFLL + ((b >> 50) & 1LL);
        r &= 0xFFFC000000000000LL;               // clear low 50 mantissa bits
        q = __longlong_as_double(r);
        q = fmin(fmax(q, -57344.0), 57344.0);
    } else {                                     // subnormal grid: 2^-16
        q = rint(x * 65536.0) * 1.52587890625e-05;
    }
    return q;
}

__device__ __forceinline__ unsigned short bfbits(double q) {
    __hip_bfloat16 h = __float2bfloat16((float)q);   // exact for grid values
    return *(unsigned short*)&h;
}

// ---------------- merged prep: quantize conv weights, fc biases; transpose+
// quantize fc weights (padded). Flat index over all segments. ----------------
__global__ void kprep(const float* __restrict__ w1, const float* __restrict__ w2,
                      const float* __restrict__ fb1, const float* __restrict__ fb2,
                      const float* __restrict__ fb3, const float* __restrict__ fw1,
                      const float* __restrict__ fw2, const float* __restrict__ fw3,
                      float* __restrict__ qw1, float* __restrict__ qw2,
                      float* __restrict__ qfb1, float* __restrict__ qfb2,
                      float* __restrict__ qfb3, float* __restrict__ Wt1,
                      float* __restrict__ Wt2, float* __restrict__ Wt3) {
    int i = blockIdx.x * 256 + threadIdx.x;
    if (i < 150) { qw1[i] = (float)fq_d((double)w1[i]); return; }
    i -= 150;
    if (i < 2400) { qw2[i] = (float)fq_d((double)w2[i]); return; }
    i -= 2400;
    if (i < 120) { qfb1[i] = (float)fq_d((double)fb1[i]); return; }
    i -= 120;
    if (i < 84) { qfb2[i] = (float)fq_d((double)fb2[i]); return; }
    i -= 84;
    if (i < 10) { qfb3[i] = (float)fq_d((double)fb3[i]); return; }
    i -= 10;
    if (i < 51200) { int k = i / 128, o = i % 128;
        Wt1[i] = (o < 120) ? (float)fq_d((double)fw1[o * 400 + k]) : 0.0f; return; }
    i -= 51200;
    if (i < 15360) { int k = i / 128, o = i % 128;
        Wt2[i] = (o < 84) ? (float)fq_d((double)fw2[o * 120 + k]) : 0.0f; return; }
    i -= 15360;
    if (i < 1344) { int k = i / 16, o = i % 16;
        Wt3[i] = (o < 10) ? (float)fq_d((double)fw3[o * 84 + k]) : 0.0f; return; }
}
#define PREP_TOTAL (150 + 2400 + 120 + 84 + 10 + 51200 + 15360 + 1344)

// ---------------- conv1: [B,1,32,32] -> fq(conv) -> [B,6,28,28] ----------------
// 3 images/block; task = (img, co, i0, half) -> 14-wide half output row.
// x tile padded to stride 33 (breaks the power-of-2 f64 bank pattern).
__global__ __launch_bounds__(256, 4) void kconv1(const float* __restrict__ x,
        const float* __restrict__ qw, __hip_bfloat16* __restrict__ c1, int nimg_total) {
    __shared__ double sx[3 * 1056];   // 3 x (32 rows x 33)
    __shared__ double sw[152];
    int t = threadIdx.x;
    int b0 = blockIdx.x * 3;
    int nimg = nimg_total - b0; if (nimg > 3) nimg = 3;
    for (int i = t; i < nimg * 1024; i += 256) {
        int img = i >> 10, idx = i & 1023;
        sx[img * 1056 + (idx >> 5) * 33 + (idx & 31)] =
            fq_d((double)x[(size_t)(b0 + img) * 1024 + idx]);
    }
    if (t < 150) sw[t] = (double)qw[t];
    __syncthreads();
    int ntask = nimg * 336;
    for (int task = t; task < ntask; task += 256) {
        int img = task / 336; int rr = task % 336;
        int co = rr / 56; int rem = rr % 56;
        int i0 = rem >> 1; int j0 = (rem & 1) * 14;
        const double* xb = &sx[img * 1056];
        const double* wp = &sw[co * 25];
        double acc[14];
        #pragma unroll
        for (int j = 0; j < 14; ++j) acc[j] = 0.0;
        #pragma unroll
        for (int u = 0; u < 5; ++u) {
            const double* xr = &xb[(i0 + u) * 33 + j0];
            double w0 = wp[u*5], w1 = wp[u*5+1], w2 = wp[u*5+2], w3 = wp[u*5+3], w4 = wp[u*5+4];
            double xv[18];
            #pragma unroll
            for (int k = 0; k < 18; ++k) xv[k] = xr[k];
            #pragma unroll
            for (int j = 0; j < 14; ++j)
                acc[j] = fma(xv[j], w0, fma(xv[j+1], w1, fma(xv[j+2], w2,
                         fma(xv[j+3], w3, fma(xv[j+4], w4, acc[j])))));
        }
        size_t base = ((size_t)(b0 + img) * 6 + co) * 784 + (size_t)i0 * 28 + j0;
        #pragma unroll
        for (int j = 0; j < 14; j += 2) {
            ushort2 pk;
            pk.x = bfbits(fq_d(acc[j])); pk.y = bfbits(fq_d(acc[j+1]));
            *(ushort2*)&c1[base + j] = pk;   // base even -> 4B aligned
        }
    }
}

// ---------------- per-channel sum / sumsq over [B,C,HW] ----------------
__global__ __launch_bounds__(256) void kstats(const __hip_bfloat16* __restrict__ d,
        double* __restrict__ st, int C, int HW, int B) {
    int c = blockIdx.x, t = threadIdx.x;
    double s = 0.0, s2 = 0.0;
    for (int b = blockIdx.y; b < B; b += gridDim.y) {
        const __hip_bfloat16* row = d + ((size_t)b * C + c) * HW;
        for (int i = t; i < HW; i += 256) {
            double v = (double)__bfloat162float(row[i]);
            s += v; s2 += v * v;
        }
    }
    __shared__ double red[256];
    red[t] = s; __syncthreads();
    for (int stp = 128; stp > 0; stp >>= 1) { if (t < stp) red[t] += red[t + stp]; __syncthreads(); }
    if (t == 0) atomicAdd(&st[2 * c], red[0]);
    __syncthreads();
    red[t] = s2; __syncthreads();
    for (int stp = 128; stp > 0; stp >>= 1) { if (t < stp) red[t] += red[t + stp]; __syncthreads(); }
    if (t == 0) atomicAdd(&st[2 * c + 1], red[0]);
}

// ---------------- finalize BN: m, rsqrt(v+eps) ----------------
__global__ void kfinal(const double* __restrict__ st, double* __restrict__ mr, int C, double N) {
    int c = threadIdx.x;
    if (c < C) {
        double m = st[2 * c] / N;
        double v = st[2 * c + 1] / N - m * m;
        mr[2 * c] = m;
        mr[2 * c + 1] = 1.0 / sqrt(v + 1e-5);
    }
}

// ---------------- bn + fq + relu + 2x2 maxpool ----------------
__global__ __launch_bounds__(256) void kbnpool(const __hip_bfloat16* __restrict__ cin,
        const double* __restrict__ mr, const float* __restrict__ g, const float* __restrict__ be,
        __hip_bfloat16* __restrict__ pout, int C, int H, int W, int total) {
    int idx = blockIdx.x * 256 + threadIdx.x;
    if (idx >= total) return;
    int Ho = H >> 1, Wo = W >> 1;
    int wo = idx % Wo; int t1 = idx / Wo;
    int ho = t1 % Ho;  int t2 = t1 / Ho;
    int c = t2 % C;    int b = t2 / C;
    double m = mr[2 * c], r = mr[2 * c + 1];
    double gg = (double)g[c], bb = (double)be[c];
    const __hip_bfloat16* base = cin + (((size_t)b * C + c) * H + 2 * ho) * W + 2 * wo;
    float best = 0.0f;   // relu(fq(v)) then max == max(0, fq(v)...)
    #pragma unroll
    for (int dy = 0; dy < 2; ++dy) {
        #pragma unroll
        for (int dx = 0; dx < 2; ++dx) {
            double v = (double)__bfloat162float(base[dy * W + dx]);
            double q = fq_d(((v - m) * r) * gg + bb);
            best = fmaxf(best, (float)q);
        }
    }
    pout[idx] = __float2bfloat16(best);
}

// ---------------- conv2: [B,6,14,14] -> fq(conv) -> [B,16,10,10] ----------------
// 2 images/block, 320 threads; task = (img, co, i0) -> 10-wide output row.
__global__ __launch_bounds__(320) void kconv2(const __hip_bfloat16* __restrict__ p1,
        const float* __restrict__ qw, __hip_bfloat16* __restrict__ c2) {
    __shared__ double sx[2352];   // 2 x [6][14][14]
    __shared__ double sw[2400];   // [16][6][5][5]
    int t = threadIdx.x;
    int b0 = blockIdx.x * 2;
    for (int i = t; i < 2352; i += 320) sx[i] = (double)__bfloat162float(p1[(size_t)b0 * 1176 + i]);
    for (int i = t; i < 2400; i += 320) sw[i] = (double)qw[i];
    __syncthreads();
    int img = t / 160, r = t % 160;
    int co = r / 10, i0 = r % 10;
    const double* xb = &sx[img * 1176];
    const double* wb = &sw[co * 150];
    double acc[10];
    #pragma unroll
    for (int j = 0; j < 10; ++j) acc[j] = 0.0;
    for (int ci = 0; ci < 6; ++ci) {
        #pragma unroll
        for (int u = 0; u < 5; ++u) {
            const double* xr = &xb[ci * 196 + (i0 + u) * 14];
            const double* wr = &wb[ci * 25 + u * 5];
            double xv[14];
            #pragma unroll
            for (int k = 0; k < 14; ++k) xv[k] = xr[k];
            double w0 = wr[0], w1 = wr[1], w2 = wr[2], w3 = wr[3], w4 = wr[4];
            #pragma unroll
            for (int j = 0; j < 10; ++j)
                acc[j] = fma(xv[j], w0, fma(xv[j+1], w1, fma(xv[j+2], w2,
                         fma(xv[j+3], w3, fma(xv[j+4], w4, acc[j])))));
        }
    }
    size_t base = ((size_t)(b0 + img) * 16 + co) * 100 + (size_t)i0 * 10;
    #pragma unroll
    for (int j = 0; j < 10; j += 2) {
        ushort2 pk;
        pk.x = bfbits(fq_d(acc[j])); pk.y = bfbits(fq_d(acc[j+1]));
        *(ushort2*)&c2[base + j] = pk;
    }
}

// ---------------- tiled FC: out = [relu?] fq( X @ Wt + qb ) ----------------
template<int IN, int OUT, int OUTP, int ROWS>
__global__ __launch_bounds__(256) void kfc(const __hip_bfloat16* __restrict__ X,
        const float* __restrict__ Wt, const float* __restrict__ qb,
        __hip_bfloat16* __restrict__ outb, float* __restrict__ outf, int do_relu) {
    constexpr int GROUPS = 256 / OUTP;
    constexpr int BT = ROWS * GROUPS;
    __shared__ double sx[BT][IN];
    int t = threadIdx.x;
    int b0 = blockIdx.x * BT;
    for (int i = t; i < BT * IN; i += 256) {
        int r = i / IN, k = i % IN;
        sx[r][k] = (double)__bfloat162float(X[(size_t)(b0 + r) * IN + k]);
    }
    __syncthreads();
    int o = t % OUTP;
    int g = t / OUTP;
    double acc[ROWS];
    double bias = (o < OUT) ? (double)qb[o] : 0.0;
    #pragma unroll
    for (int r = 0; r < ROWS; ++r) acc[r] = bias;
    #pragma unroll 4
    for (int k = 0; k < IN; ++k) {
        double w = (double)Wt[k * OUTP + o];   // coalesced, L2-resident
        #pragma unroll
        for (int r = 0; r < ROWS; ++r)
            acc[r] = fma(sx[g * ROWS + r][k], w, acc[r]);  // LDS broadcast reads
    }
    if (o < OUT) {
        #pragma unroll
        for (int r = 0; r < ROWS; ++r) {
            double q = fq_d(acc[r]);
            if (do_relu && q < 0.0) q = 0.0;
            size_t b = (size_t)(b0 + g * ROWS + r);
            if (outf) outf[b * OUT + o] = (float)q;
            else      outb[b * OUT + o] = __float2bfloat16((float)q);
        }
    }
}

// ---------------------------------------------------------------------------
extern "C" void kernel_launch(void* const* d_in, const int* in_sizes, int n_in,
                              void* d_out, int out_size, void* d_ws, size_t ws_size,
                              hipStream_t stream) {
    const float* x   = (const float*)d_in[0];
    const float* w1  = (const float*)d_in[1];
    const float* g1  = (const float*)d_in[2];
    const float* be1 = (const float*)d_in[3];
    const float* w2  = (const float*)d_in[4];
    const float* g2  = (const float*)d_in[5];
    const float* be2 = (const float*)d_in[6];
    const float* fw1 = (const float*)d_in[7];
    const float* fb1 = (const float*)d_in[8];
    const float* fw2 = (const float*)d_in[9];
    const float* fb2 = (const float*)d_in[10];
    const float* fw3 = (const float*)d_in[11];
    const float* fb3 = (const float*)d_in[12];

    char* ws = (char*)d_ws;
    double* stats1 = (double*)(ws + 0);      // 12 dbl
    double* mr1    = (double*)(ws + 256);    // 12 dbl
    double* stats2 = (double*)(ws + 512);    // 32 dbl
    double* mr2    = (double*)(ws + 768);    // 32 dbl
    float* qw1  = (float*)(ws + 1024);       // 150
    float* qw2  = (float*)(ws + 2048);       // 2400 (ends 11648)
    float* qfb1 = (float*)(ws + 12288);      // 120
    float* qfb2 = (float*)(ws + 12800);      // 84
    float* qfb3 = (float*)(ws + 13184);      // 10
    float* Wt1  = (float*)(ws + 16384);      // 400*128 (ends 221184)
    float* Wt2  = (float*)(ws + 221184);     // 120*128 (ends 282624)
    float* Wt3  = (float*)(ws + 282624);     // 84*16   (ends 288000)
    // big buffers (aliased by liveness)
    __hip_bfloat16* bufA = (__hip_bfloat16*)(ws + 294912);    // c1 [B,6,28,28] then c2 [B,16,10,10]
    __hip_bfloat16* bufB = (__hip_bfloat16*)(ws + 77365248);  // p1 [B,6,14,14] then p2 [B,400]
    __hip_bfloat16* bufC = (__hip_bfloat16*)(ws + 294912);    // a1 [B,120] (aliases dead bufA)
    __hip_bfloat16* bufD = (__hip_bfloat16*)(ws + 294912 + 2097152); // a2 [B,84]

    hipMemsetAsync(ws, 0, 1024, stream);

    kprep<<<(PREP_TOTAL + 255) / 256, 256, 0, stream>>>(
        w1, w2, fb1, fb2, fb3, fw1, fw2, fw3,
        qw1, qw2, qfb1, qfb2, qfb3, Wt1, Wt2, Wt3);

    // conv1 + fq -> bufA [B,6,28,28]   (3 images per block)
    kconv1<<<(BATCH + 2) / 3, 256, 0, stream>>>(x, qw1, bufA, BATCH);
    kstats<<<dim3(6, 256), 256, 0, stream>>>(bufA, stats1, 6, 784, BATCH);
    kfinal<<<1, 32, 0, stream>>>(stats1, mr1, 6, (double)BATCH * 784.0);
    {
        int total = BATCH * 6 * 14 * 14;
        kbnpool<<<(total + 255) / 256, 256, 0, stream>>>(bufA, mr1, g1, be1, bufB, 6, 28, 28, total);
    }
    // conv2 + fq -> bufA [B,16,10,10]  (2 images per block, 320 threads)
    kconv2<<<BATCH / 2, 320, 0, stream>>>(bufB, qw2, bufA);
    kstats<<<dim3(16, 256), 256, 0, stream>>>(bufA, stats2, 16, 100, BATCH);
    kfinal<<<1, 32, 0, stream>>>(stats2, mr2, 16, (double)BATCH * 100.0);
    {
        int total = BATCH * 16 * 5 * 5;
        kbnpool<<<(total + 255) / 256, 256, 0, stream>>>(bufA, mr2, g2, be2, bufB, 16, 10, 10, total);
    }
    // fc1 (+relu): [B,400] -> [B,120]
    kfc<400, 120, 128, 8><<<BATCH / 16, 256, 0, stream>>>(bufB, Wt1, qfb1, bufC, (float*)nullptr, 1);
    // fc2 (+relu): [B,120] -> [B,84]
    kfc<120, 84, 128, 8><<<BATCH / 16, 256, 0, stream>>>(bufC, Wt2, qfb2, bufD, (float*)nullptr, 1);
    // fc3: [B,84] -> [B,10] float out
    kfc<84, 10, 16, 1><<<BATCH / 16, 256, 0, stream>>>(bufD, Wt3, qfb3, (__hip_bfloat16*)nullptr, (float*)d_out, 0);
}

// Round 5
// 815.219 us; speedup vs baseline: 1.4123x; 1.4123x over previous
//
#include <hip/hip_runtime.h>
#include <hip/hip_bf16.h>

// ---------------------------------------------------------------------------
// QLenet forward, exact-math strategy (round-0 notes):
//   All fq() outputs are e5m2 grid values (<=3 significant bits). Products of
//   two grid values have <=6-bit mantissas; dot sums (<=400 terms, bounded
//   exponent span) are EXACT in f64 -> order-independent -> matches float64
//   numpy reference. Intermediates stored as bf16 (exact for grid values).
//   (f32 accumulation is NOT safe: exact-tie sums occur at ~1% rate and f32
//   roundoff flips them by a full e5m2 step >> 0.04 threshold.)
// Round 4 -> 5: __launch_bounds__(256,4) on kconv1 capped VGPR at 64 ->
//   acc[14]+xv[18] spilled to scratch (FETCH 16.5MB -> 1.17GB, 700us).
//   Relaxed to (256,3): cap ~170 VGPR, need ~110 -> no spill, >=3 waves/EU.
// ---------------------------------------------------------------------------

#define BATCH 8192

// fq: round to FP(e5m2) nearest-even, subnormal granule 2^-16, clip +-57344.
// Normal path (|x| >= 2^-14): integer round-to-nearest-even of the f64
// mantissa to 2 bits; carry propagates into the exponent automatically.
__device__ __forceinline__ double fq_d(double x) {
    long long b = __double_as_longlong(x);
    long long ab = b & 0x7fffffffffffffffLL;
    if (ab == 0) return x;                       // +-0 preserved (ref: where(ax>0,...))
    double q;
    if (ab >= 0x3F10000000000000LL) {            // |x| >= 2^-14
        long long r = b + 0x0001FFFFFFFFFFFFLL + ((b >> 50) & 1LL);
        r &= 0xFFFC000000000000LL;               // clear low 50 mantissa bits
        q = __longlong_as_double(r);
        q = fmin(fmax(q, -57344.0), 57344.0);
    } else {                                     // subnormal grid: 2^-16
        q = rint(x * 65536.0) * 1.52587890625e-05;
    }
    return q;
}

__device__ __forceinline__ unsigned short bfbits(double q) {
    __hip_bfloat16 h = __float2bfloat16((float)q);   // exact for grid values
    return *(unsigned short*)&h;
}

// ---------------- merged prep: quantize conv weights, fc biases; transpose+
// quantize fc weights (padded). Flat index over all segments. ----------------
__global__ void kprep(const float* __restrict__ w1, const float* __restrict__ w2,
                      const float* __restrict__ fb1, const float* __restrict__ fb2,
                      const float* __restrict__ fb3, const float* __restrict__ fw1,
                      const float* __restrict__ fw2, const float* __restrict__ fw3,
                      float* __restrict__ qw1, float* __restrict__ qw2,
                      float* __restrict__ qfb1, float* __restrict__ qfb2,
                      float* __restrict__ qfb3, float* __restrict__ Wt1,
                      float* __restrict__ Wt2, float* __restrict__ Wt3) {
    int i = blockIdx.x * 256 + threadIdx.x;
    if (i < 150) { qw1[i] = (float)fq_d((double)w1[i]); return; }
    i -= 150;
    if (i < 2400) { qw2[i] = (float)fq_d((double)w2[i]); return; }
    i -= 2400;
    if (i < 120) { qfb1[i] = (float)fq_d((double)fb1[i]); return; }
    i -= 120;
    if (i < 84) { qfb2[i] = (float)fq_d((double)fb2[i]); return; }
    i -= 84;
    if (i < 10) { qfb3[i] = (float)fq_d((double)fb3[i]); return; }
    i -= 10;
    if (i < 51200) { int k = i / 128, o = i % 128;
        Wt1[i] = (o < 120) ? (float)fq_d((double)fw1[o * 400 + k]) : 0.0f; return; }
    i -= 51200;
    if (i < 15360) { int k = i / 128, o = i % 128;
        Wt2[i] = (o < 84) ? (float)fq_d((double)fw2[o * 120 + k]) : 0.0f; return; }
    i -= 15360;
    if (i < 1344) { int k = i / 16, o = i % 16;
        Wt3[i] = (o < 10) ? (float)fq_d((double)fw3[o * 84 + k]) : 0.0f; return; }
}
#define PREP_TOTAL (150 + 2400 + 120 + 84 + 10 + 51200 + 15360 + 1344)

// ---------------- conv1: [B,1,32,32] -> fq(conv) -> [B,6,28,28] ----------------
// 3 images/block; task = (img, co, i0, half) -> 14-wide half output row.
// x tile padded to stride 33 (breaks the power-of-2 f64 bank pattern).
__global__ __launch_bounds__(256, 3) void kconv1(const float* __restrict__ x,
        const float* __restrict__ qw, __hip_bfloat16* __restrict__ c1, int nimg_total) {
    __shared__ double sx[3 * 1056];   // 3 x (32 rows x 33)
    __shared__ double sw[152];
    int t = threadIdx.x;
    int b0 = blockIdx.x * 3;
    int nimg = nimg_total - b0; if (nimg > 3) nimg = 3;
    for (int i = t; i < nimg * 1024; i += 256) {
        int img = i >> 10, idx = i & 1023;
        sx[img * 1056 + (idx >> 5) * 33 + (idx & 31)] =
            fq_d((double)x[(size_t)(b0 + img) * 1024 + idx]);
    }
    if (t < 150) sw[t] = (double)qw[t];
    __syncthreads();
    int ntask = nimg * 336;
    for (int task = t; task < ntask; task += 256) {
        int img = task / 336; int rr = task % 336;
        int co = rr / 56; int rem = rr % 56;
        int i0 = rem >> 1; int j0 = (rem & 1) * 14;
        const double* xb = &sx[img * 1056];
        const double* wp = &sw[co * 25];
        double acc[14];
        #pragma unroll
        for (int j = 0; j < 14; ++j) acc[j] = 0.0;
        #pragma unroll
        for (int u = 0; u < 5; ++u) {
            const double* xr = &xb[(i0 + u) * 33 + j0];
            double w0 = wp[u*5], w1 = wp[u*5+1], w2 = wp[u*5+2], w3 = wp[u*5+3], w4 = wp[u*5+4];
            double xv[18];
            #pragma unroll
            for (int k = 0; k < 18; ++k) xv[k] = xr[k];
            #pragma unroll
            for (int j = 0; j < 14; ++j)
                acc[j] = fma(xv[j], w0, fma(xv[j+1], w1, fma(xv[j+2], w2,
                         fma(xv[j+3], w3, fma(xv[j+4], w4, acc[j])))));
        }
        size_t base = ((size_t)(b0 + img) * 6 + co) * 784 + (size_t)i0 * 28 + j0;
        #pragma unroll
        for (int j = 0; j < 14; j += 2) {
            ushort2 pk;
            pk.x = bfbits(fq_d(acc[j])); pk.y = bfbits(fq_d(acc[j+1]));
            *(ushort2*)&c1[base + j] = pk;   // base even -> 4B aligned
        }
    }
}

// ---------------- per-channel sum / sumsq over [B,C,HW] ----------------
__global__ __launch_bounds__(256) void kstats(const __hip_bfloat16* __restrict__ d,
        double* __restrict__ st, int C, int HW, int B) {
    int c = blockIdx.x, t = threadIdx.x;
    double s = 0.0, s2 = 0.0;
    for (int b = blockIdx.y; b < B; b += gridDim.y) {
        const __hip_bfloat16* row = d + ((size_t)b * C + c) * HW;
        for (int i = t; i < HW; i += 256) {
            double v = (double)__bfloat162float(row[i]);
            s += v; s2 += v * v;
        }
    }
    __shared__ double red[256];
    red[t] = s; __syncthreads();
    for (int stp = 128; stp > 0; stp >>= 1) { if (t < stp) red[t] += red[t + stp]; __syncthreads(); }
    if (t == 0) atomicAdd(&st[2 * c], red[0]);
    __syncthreads();
    red[t] = s2; __syncthreads();
    for (int stp = 128; stp > 0; stp >>= 1) { if (t < stp) red[t] += red[t + stp]; __syncthreads(); }
    if (t == 0) atomicAdd(&st[2 * c + 1], red[0]);
}

// ---------------- finalize BN: m, rsqrt(v+eps) ----------------
__global__ void kfinal(const double* __restrict__ st, double* __restrict__ mr, int C, double N) {
    int c = threadIdx.x;
    if (c < C) {
        double m = st[2 * c] / N;
        double v = st[2 * c + 1] / N - m * m;
        mr[2 * c] = m;
        mr[2 * c + 1] = 1.0 / sqrt(v + 1e-5);
    }
}

// ---------------- bn + fq + relu + 2x2 maxpool ----------------
__global__ __launch_bounds__(256) void kbnpool(const __hip_bfloat16* __restrict__ cin,
        const double* __restrict__ mr, const float* __restrict__ g, const float* __restrict__ be,
        __hip_bfloat16* __restrict__ pout, int C, int H, int W, int total) {
    int idx = blockIdx.x * 256 + threadIdx.x;
    if (idx >= total) return;
    int Ho = H >> 1, Wo = W >> 1;
    int wo = idx % Wo; int t1 = idx / Wo;
    int ho = t1 % Ho;  int t2 = t1 / Ho;
    int c = t2 % C;    int b = t2 / C;
    double m = mr[2 * c], r = mr[2 * c + 1];
    double gg = (double)g[c], bb = (double)be[c];
    const __hip_bfloat16* base = cin + (((size_t)b * C + c) * H + 2 * ho) * W + 2 * wo;
    float best = 0.0f;   // relu(fq(v)) then max == max(0, fq(v)...)
    #pragma unroll
    for (int dy = 0; dy < 2; ++dy) {
        #pragma unroll
        for (int dx = 0; dx < 2; ++dx) {
            double v = (double)__bfloat162float(base[dy * W + dx]);
            double q = fq_d(((v - m) * r) * gg + bb);
            best = fmaxf(best, (float)q);
        }
    }
    pout[idx] = __float2bfloat16(best);
}

// ---------------- conv2: [B,6,14,14] -> fq(conv) -> [B,16,10,10] ----------------
// 2 images/block, 320 threads; task = (img, co, i0) -> 10-wide output row.
__global__ __launch_bounds__(320) void kconv2(const __hip_bfloat16* __restrict__ p1,
        const float* __restrict__ qw, __hip_bfloat16* __restrict__ c2) {
    __shared__ double sx[2352];   // 2 x [6][14][14]
    __shared__ double sw[2400];   // [16][6][5][5]
    int t = threadIdx.x;
    int b0 = blockIdx.x * 2;
    for (int i = t; i < 2352; i += 320) sx[i] = (double)__bfloat162float(p1[(size_t)b0 * 1176 + i]);
    for (int i = t; i < 2400; i += 320) sw[i] = (double)qw[i];
    __syncthreads();
    int img = t / 160, r = t % 160;
    int co = r / 10, i0 = r % 10;
    const double* xb = &sx[img * 1176];
    const double* wb = &sw[co * 150];
    double acc[10];
    #pragma unroll
    for (int j = 0; j < 10; ++j) acc[j] = 0.0;
    for (int ci = 0; ci < 6; ++ci) {
        #pragma unroll
        for (int u = 0; u < 5; ++u) {
            const double* xr = &xb[ci * 196 + (i0 + u) * 14];
            const double* wr = &wb[ci * 25 + u * 5];
            double xv[14];
            #pragma unroll
            for (int k = 0; k < 14; ++k) xv[k] = xr[k];
            double w0 = wr[0], w1 = wr[1], w2 = wr[2], w3 = wr[3], w4 = wr[4];
            #pragma unroll
            for (int j = 0; j < 10; ++j)
                acc[j] = fma(xv[j], w0, fma(xv[j+1], w1, fma(xv[j+2], w2,
                         fma(xv[j+3], w3, fma(xv[j+4], w4, acc[j])))));
        }
    }
    size_t base = ((size_t)(b0 + img) * 16 + co) * 100 + (size_t)i0 * 10;
    #pragma unroll
    for (int j = 0; j < 10; j += 2) {
        ushort2 pk;
        pk.x = bfbits(fq_d(acc[j])); pk.y = bfbits(fq_d(acc[j+1]));
        *(ushort2*)&c2[base + j] = pk;
    }
}

// ---------------- tiled FC: out = [relu?] fq( X @ Wt + qb ) ----------------
template<int IN, int OUT, int OUTP, int ROWS>
__global__ __launch_bounds__(256) void kfc(const __hip_bfloat16* __restrict__ X,
        const float* __restrict__ Wt, const float* __restrict__ qb,
        __hip_bfloat16* __restrict__ outb, float* __restrict__ outf, int do_relu) {
    constexpr int GROUPS = 256 / OUTP;
    constexpr int BT = ROWS * GROUPS;
    __shared__ double sx[BT][IN];
    int t = threadIdx.x;
    int b0 = blockIdx.x * BT;
    for (int i = t; i < BT * IN; i += 256) {
        int r = i / IN, k = i % IN;
        sx[r][k] = (double)__bfloat162float(X[(size_t)(b0 + r) * IN + k]);
    }
    __syncthreads();
    int o = t % OUTP;
    int g = t / OUTP;
    double acc[ROWS];
    double bias = (o < OUT) ? (double)qb[o] : 0.0;
    #pragma unroll
    for (int r = 0; r < ROWS; ++r) acc[r] = bias;
    #pragma unroll 4
    for (int k = 0; k < IN; ++k) {
        double w = (double)Wt[k * OUTP + o];   // coalesced, L2-resident
        #pragma unroll
        for (int r = 0; r < ROWS; ++r)
            acc[r] = fma(sx[g * ROWS + r][k], w, acc[r]);  // LDS broadcast reads
    }
    if (o < OUT) {
        #pragma unroll
        for (int r = 0; r < ROWS; ++r) {
            double q = fq_d(acc[r]);
            if (do_relu && q < 0.0) q = 0.0;
            size_t b = (size_t)(b0 + g * ROWS + r);
            if (outf) outf[b * OUT + o] = (float)q;
            else      outb[b * OUT + o] = __float2bfloat16((float)q);
        }
    }
}

// ---------------------------------------------------------------------------
extern "C" void kernel_launch(void* const* d_in, const int* in_sizes, int n_in,
                              void* d_out, int out_size, void* d_ws, size_t ws_size,
                              hipStream_t stream) {
    const float* x   = (const float*)d_in[0];
    const float* w1  = (const float*)d_in[1];
    const float* g1  = (const float*)d_in[2];
    const float* be1 = (const float*)d_in[3];
    const float* w2  = (const float*)d_in[4];
    const float* g2  = (const float*)d_in[5];
    const float* be2 = (const float*)d_in[6];
    const float* fw1 = (const float*)d_in[7];
    const float* fb1 = (const float*)d_in[8];
    const float* fw2 = (const float*)d_in[9];
    const float* fb2 = (const float*)d_in[10];
    const float* fw3 = (const float*)d_in[11];
    const float* fb3 = (const float*)d_in[12];

    char* ws = (char*)d_ws;
    double* stats1 = (double*)(ws + 0);      // 12 dbl
    double* mr1    = (double*)(ws + 256);    // 12 dbl
    double* stats2 = (double*)(ws + 512);    // 32 dbl
    double* mr2    = (double*)(ws + 768);    // 32 dbl
    float* qw1  = (float*)(ws + 1024);       // 150
    float* qw2  = (float*)(ws + 2048);       // 2400 (ends 11648)
    float* qfb1 = (float*)(ws + 12288);      // 120
    float* qfb2 = (float*)(ws + 12800);      // 84
    float* qfb3 = (float*)(ws + 13184);      // 10
    float* Wt1  = (float*)(ws + 16384);      // 400*128 (ends 221184)
    float* Wt2  = (float*)(ws + 221184);     // 120*128 (ends 282624)
    float* Wt3  = (float*)(ws + 282624);     // 84*16   (ends 288000)
    // big buffers (aliased by liveness)
    __hip_bfloat16* bufA = (__hip_bfloat16*)(ws + 294912);    // c1 [B,6,28,28] then c2 [B,16,10,10]
    __hip_bfloat16* bufB = (__hip_bfloat16*)(ws + 77365248);  // p1 [B,6,14,14] then p2 [B,400]
    __hip_bfloat16* bufC = (__hip_bfloat16*)(ws + 294912);    // a1 [B,120] (aliases dead bufA)
    __hip_bfloat16* bufD = (__hip_bfloat16*)(ws + 294912 + 2097152); // a2 [B,84]

    hipMemsetAsync(ws, 0, 1024, stream);

    kprep<<<(PREP_TOTAL + 255) / 256, 256, 0, stream>>>(
        w1, w2, fb1, fb2, fb3, fw1, fw2, fw3,
        qw1, qw2, qfb1, qfb2, qfb3, Wt1, Wt2, Wt3);

    // conv1 + fq -> bufA [B,6,28,28]   (3 images per block)
    kconv1<<<(BATCH + 2) / 3, 256, 0, stream>>>(x, qw1, bufA, BATCH);
    kstats<<<dim3(6, 256), 256, 0, stream>>>(bufA, stats1, 6, 784, BATCH);
    kfinal<<<1, 32, 0, stream>>>(stats1, mr1, 6, (double)BATCH * 784.0);
    {
        int total = BATCH * 6 * 14 * 14;
        kbnpool<<<(total + 255) / 256, 256, 0, stream>>>(bufA, mr1, g1, be1, bufB, 6, 28, 28, total);
    }
    // conv2 + fq -> bufA [B,16,10,10]  (2 images per block, 320 threads)
    kconv2<<<BATCH / 2, 320, 0, stream>>>(bufB, qw2, bufA);
    kstats<<<dim3(16, 256), 256, 0, stream>>>(bufA, stats2, 16, 100, BATCH);
    kfinal<<<1, 32, 0, stream>>>(stats2, mr2, 16, (double)BATCH * 100.0);
    {
        int total = BATCH * 16 * 5 * 5;
        kbnpool<<<(total + 255) / 256, 256, 0, stream>>>(bufA, mr2, g2, be2, bufB, 16, 10, 10, total);
    }
    // fc1 (+relu): [B,400] -> [B,120]
    kfc<400, 120, 128, 8><<<BATCH / 16, 256, 0, stream>>>(bufB, Wt1, qfb1, bufC, (float*)nullptr, 1);
    // fc2 (+relu): [B,120] -> [B,84]
    kfc<120, 84, 128, 8><<<BATCH / 16, 256, 0, stream>>>(bufC, Wt2, qfb2, bufD, (float*)nullptr, 1);
    // fc3: [B,84] -> [B,10] float out
    kfc<84, 10, 16, 1><<<BATCH / 16, 256, 0, stream>>>(bufD, Wt3, qfb3, (__hip_bfloat16*)nullptr, (float*)d_out, 0);
}

// Round 6
// 564.174 us; speedup vs baseline: 2.0407x; 1.4450x over previous
//
#include <hip/hip_runtime.h>
#include <hip/hip_bf16.h>

// ---------------------------------------------------------------------------
// QLenet forward, exact-math strategy (round-0 notes):
//   All fq() outputs are e5m2 grid values (<=3 significant bits). Products of
//   two grid values have <=6-bit mantissas; dot sums (<=400 terms, bounded
//   exponent span) are EXACT in f64 -> order-independent -> matches float64
//   numpy reference. Intermediates stored as bf16 (exact for grid values).
// Round 5 -> 6: kconv1 spill history: r3 192VGPR/11%occ; (256,4) cap64 ->
//   1.2GB scratch; (256,3) cap84 -> still 1.2GB scratch. Fix the working set
//   instead of the bound: 2-row x 7-col tile (x-row feeds both output rows
//   via rotated w regs) -> live set ~35 f64 ~= 100 VGPR, no launch_bounds
//   min-waves. Same FMA:LDS ratio, half the accumulator pressure.
// ---------------------------------------------------------------------------

#define BATCH 8192

// fq: round to FP(e5m2) nearest-even, subnormal granule 2^-16, clip +-57344.
// Normal path (|x| >= 2^-14): integer round-to-nearest-even of the f64
// mantissa to 2 bits; carry propagates into the exponent automatically.
__device__ __forceinline__ double fq_d(double x) {
    long long b = __double_as_longlong(x);
    long long ab = b & 0x7fffffffffffffffLL;
    if (ab == 0) return x;                       // +-0 preserved (ref: where(ax>0,...))
    double q;
    if (ab >= 0x3F10000000000000LL) {            // |x| >= 2^-14
        long long r = b + 0x0001FFFFFFFFFFFFLL + ((b >> 50) & 1LL);
        r &= 0xFFFC000000000000LL;               // clear low 50 mantissa bits
        q = __longlong_as_double(r);
        q = fmin(fmax(q, -57344.0), 57344.0);
    } else {                                     // subnormal grid: 2^-16
        q = rint(x * 65536.0) * 1.52587890625e-05;
    }
    return q;
}

__device__ __forceinline__ unsigned short bfbits(double q) {
    __hip_bfloat16 h = __float2bfloat16((float)q);   // exact for grid values
    return *(unsigned short*)&h;
}

// ---------------- merged prep: quantize conv weights, fc biases; transpose+
// quantize fc weights (padded). Flat index over all segments. ----------------
__global__ void kprep(const float* __restrict__ w1, const float* __restrict__ w2,
                      const float* __restrict__ fb1, const float* __restrict__ fb2,
                      const float* __restrict__ fb3, const float* __restrict__ fw1,
                      const float* __restrict__ fw2, const float* __restrict__ fw3,
                      float* __restrict__ qw1, float* __restrict__ qw2,
                      float* __restrict__ qfb1, float* __restrict__ qfb2,
                      float* __restrict__ qfb3, float* __restrict__ Wt1,
                      float* __restrict__ Wt2, float* __restrict__ Wt3) {
    int i = blockIdx.x * 256 + threadIdx.x;
    if (i < 150) { qw1[i] = (float)fq_d((double)w1[i]); return; }
    i -= 150;
    if (i < 2400) { qw2[i] = (float)fq_d((double)w2[i]); return; }
    i -= 2400;
    if (i < 120) { qfb1[i] = (float)fq_d((double)fb1[i]); return; }
    i -= 120;
    if (i < 84) { qfb2[i] = (float)fq_d((double)fb2[i]); return; }
    i -= 84;
    if (i < 10) { qfb3[i] = (float)fq_d((double)fb3[i]); return; }
    i -= 10;
    if (i < 51200) { int k = i / 128, o = i % 128;
        Wt1[i] = (o < 120) ? (float)fq_d((double)fw1[o * 400 + k]) : 0.0f; return; }
    i -= 51200;
    if (i < 15360) { int k = i / 128, o = i % 128;
        Wt2[i] = (o < 84) ? (float)fq_d((double)fw2[o * 120 + k]) : 0.0f; return; }
    i -= 15360;
    if (i < 1344) { int k = i / 16, o = i % 16;
        Wt3[i] = (o < 10) ? (float)fq_d((double)fw3[o * 84 + k]) : 0.0f; return; }
}
#define PREP_TOTAL (150 + 2400 + 120 + 84 + 10 + 51200 + 15360 + 1344)

// ---------------- conv1: [B,1,32,32] -> fq(conv) -> [B,6,28,28] ----------------
// 3 images/block; task = (img, co, rowpair, colchunk) -> 2x7 output tile.
// Each loaded x-row (xv[11]) feeds both output rows: w[u] for row0 (u<5),
// w[u-1] (rotated regs) for row1 (u>=1). Live: acc14+xv11+w10 = 35 f64.
// x tile padded to stride 33 (breaks the power-of-2 f64 bank pattern).
__global__ __launch_bounds__(256) void kconv1(const float* __restrict__ x,
        const float* __restrict__ qw, __hip_bfloat16* __restrict__ c1, int nimg_total) {
    __shared__ double sx[3 * 1056];   // 3 x (32 rows x 33)
    __shared__ double sw[152];
    int t = threadIdx.x;
    int b0 = blockIdx.x * 3;
    int nimg = nimg_total - b0; if (nimg > 3) nimg = 3;
    for (int i = t; i < nimg * 1024; i += 256) {
        int img = i >> 10, idx = i & 1023;
        sx[img * 1056 + (idx >> 5) * 33 + (idx & 31)] =
            fq_d((double)x[(size_t)(b0 + img) * 1024 + idx]);
    }
    if (t < 150) sw[t] = (double)qw[t];
    __syncthreads();
    int ntask = nimg * 336;           // 6 co x 14 rowpairs x 4 colchunks
    for (int task = t; task < ntask; task += 256) {
        int img = task / 336; int rr = task % 336;
        int co = rr / 56; int rem = rr % 56;
        int i0 = (rem >> 2) * 2;      // 0,2,...,26
        int j0 = (rem & 3) * 7;       // 0,7,14,21
        const double* xb = &sx[img * 1056];
        const double* wp = &sw[co * 25];
        double a0[7], a1[7];
        #pragma unroll
        for (int j = 0; j < 7; ++j) { a0[j] = 0.0; a1[j] = 0.0; }
        double wr[5], wq[5];
        #pragma unroll
        for (int u = 0; u < 6; ++u) {
            const double* xr = &xb[(i0 + u) * 33 + j0];
            double xv[11];
            #pragma unroll
            for (int k = 0; k < 11; ++k) xv[k] = xr[k];
            if (u < 5) {
                #pragma unroll
                for (int tt = 0; tt < 5; ++tt) wr[tt] = wp[u * 5 + tt];
                #pragma unroll
                for (int j = 0; j < 7; ++j)
                    a0[j] = fma(xv[j], wr[0], fma(xv[j+1], wr[1], fma(xv[j+2], wr[2],
                            fma(xv[j+3], wr[3], fma(xv[j+4], wr[4], a0[j])))));
            }
            if (u >= 1) {
                #pragma unroll
                for (int j = 0; j < 7; ++j)
                    a1[j] = fma(xv[j], wq[0], fma(xv[j+1], wq[1], fma(xv[j+2], wq[2],
                            fma(xv[j+3], wq[3], fma(xv[j+4], wq[4], a1[j])))));
            }
            #pragma unroll
            for (int tt = 0; tt < 5; ++tt) wq[tt] = wr[tt];   // SSA rotate
        }
        size_t base = ((size_t)(b0 + img) * 6 + co) * 784 + (size_t)i0 * 28 + j0;
        #pragma unroll
        for (int j = 0; j < 7; ++j) {
            c1[base + j]      = __hip_bfloat16(); // placeholder overwritten below
        }
        #pragma unroll
        for (int j = 0; j < 7; ++j) {
            ((unsigned short*)c1)[base + j]      = bfbits(fq_d(a0[j]));
            ((unsigned short*)c1)[base + 28 + j] = bfbits(fq_d(a1[j]));
        }
    }
}

// ---------------- per-channel sum / sumsq over [B,C,HW] ----------------
__global__ __launch_bounds__(256) void kstats(const __hip_bfloat16* __restrict__ d,
        double* __restrict__ st, int C, int HW, int B) {
    int c = blockIdx.x, t = threadIdx.x;
    double s = 0.0, s2 = 0.0;
    for (int b = blockIdx.y; b < B; b += gridDim.y) {
        const __hip_bfloat16* row = d + ((size_t)b * C + c) * HW;
        for (int i = t; i < HW; i += 256) {
            double v = (double)__bfloat162float(row[i]);
            s += v; s2 += v * v;
        }
    }
    __shared__ double red[256];
    red[t] = s; __syncthreads();
    for (int stp = 128; stp > 0; stp >>= 1) { if (t < stp) red[t] += red[t + stp]; __syncthreads(); }
    if (t == 0) atomicAdd(&st[2 * c], red[0]);
    __syncthreads();
    red[t] = s2; __syncthreads();
    for (int stp = 128; stp > 0; stp >>= 1) { if (t < stp) red[t] += red[t + stp]; __syncthreads(); }
    if (t == 0) atomicAdd(&st[2 * c + 1], red[0]);
}

// ---------------- finalize BN: m, rsqrt(v+eps) ----------------
__global__ void kfinal(const double* __restrict__ st, double* __restrict__ mr, int C, double N) {
    int c = threadIdx.x;
    if (c < C) {
        double m = st[2 * c] / N;
        double v = st[2 * c + 1] / N - m * m;
        mr[2 * c] = m;
        mr[2 * c + 1] = 1.0 / sqrt(v + 1e-5);
    }
}

// ---------------- bn + fq + relu + 2x2 maxpool ----------------
__global__ __launch_bounds__(256) void kbnpool(const __hip_bfloat16* __restrict__ cin,
        const double* __restrict__ mr, const float* __restrict__ g, const float* __restrict__ be,
        __hip_bfloat16* __restrict__ pout, int C, int H, int W, int total) {
    int idx = blockIdx.x * 256 + threadIdx.x;
    if (idx >= total) return;
    int Ho = H >> 1, Wo = W >> 1;
    int wo = idx % Wo; int t1 = idx / Wo;
    int ho = t1 % Ho;  int t2 = t1 / Ho;
    int c = t2 % C;    int b = t2 / C;
    double m = mr[2 * c], r = mr[2 * c + 1];
    double gg = (double)g[c], bb = (double)be[c];
    const __hip_bfloat16* base = cin + (((size_t)b * C + c) * H + 2 * ho) * W + 2 * wo;
    float best = 0.0f;   // relu(fq(v)) then max == max(0, fq(v)...)
    #pragma unroll
    for (int dy = 0; dy < 2; ++dy) {
        #pragma unroll
        for (int dx = 0; dx < 2; ++dx) {
            double v = (double)__bfloat162float(base[dy * W + dx]);
            double q = fq_d(((v - m) * r) * gg + bb);
            best = fmaxf(best, (float)q);
        }
    }
    pout[idx] = __float2bfloat16(best);
}

// ---------------- conv2: [B,6,14,14] -> fq(conv) -> [B,16,10,10] ----------------
// 2 images/block, 320 threads; task = (img, co, i0) -> 10-wide output row.
__global__ __launch_bounds__(320) void kconv2(const __hip_bfloat16* __restrict__ p1,
        const float* __restrict__ qw, __hip_bfloat16* __restrict__ c2) {
    __shared__ double sx[2352];   // 2 x [6][14][14]
    __shared__ double sw[2400];   // [16][6][5][5]
    int t = threadIdx.x;
    int b0 = blockIdx.x * 2;
    for (int i = t; i < 2352; i += 320) sx[i] = (double)__bfloat162float(p1[(size_t)b0 * 1176 + i]);
    for (int i = t; i < 2400; i += 320) sw[i] = (double)qw[i];
    __syncthreads();
    int img = t / 160, r = t % 160;
    int co = r / 10, i0 = r % 10;
    const double* xb = &sx[img * 1176];
    const double* wb = &sw[co * 150];
    double acc[10];
    #pragma unroll
    for (int j = 0; j < 10; ++j) acc[j] = 0.0;
    for (int ci = 0; ci < 6; ++ci) {
        #pragma unroll
        for (int u = 0; u < 5; ++u) {
            const double* xr = &xb[ci * 196 + (i0 + u) * 14];
            const double* wr = &wb[ci * 25 + u * 5];
            double xv[14];
            #pragma unroll
            for (int k = 0; k < 14; ++k) xv[k] = xr[k];
            double w0 = wr[0], w1 = wr[1], w2 = wr[2], w3 = wr[3], w4 = wr[4];
            #pragma unroll
            for (int j = 0; j < 10; ++j)
                acc[j] = fma(xv[j], w0, fma(xv[j+1], w1, fma(xv[j+2], w2,
                         fma(xv[j+3], w3, fma(xv[j+4], w4, acc[j])))));
        }
    }
    size_t base = ((size_t)(b0 + img) * 16 + co) * 100 + (size_t)i0 * 10;
    #pragma unroll
    for (int j = 0; j < 10; j += 2) {
        ushort2 pk;
        pk.x = bfbits(fq_d(acc[j])); pk.y = bfbits(fq_d(acc[j+1]));
        *(ushort2*)&c2[base + j] = pk;
    }
}

// ---------------- tiled FC: out = [relu?] fq( X @ Wt + qb ) ----------------
template<int IN, int OUT, int OUTP, int ROWS>
__global__ __launch_bounds__(256) void kfc(const __hip_bfloat16* __restrict__ X,
        const float* __restrict__ Wt, const float* __restrict__ qb,
        __hip_bfloat16* __restrict__ outb, float* __restrict__ outf, int do_relu) {
    constexpr int GROUPS = 256 / OUTP;
    constexpr int BT = ROWS * GROUPS;
    __shared__ double sx[BT][IN];
    int t = threadIdx.x;
    int b0 = blockIdx.x * BT;
    for (int i = t; i < BT * IN; i += 256) {
        int r = i / IN, k = i % IN;
        sx[r][k] = (double)__bfloat162float(X[(size_t)(b0 + r) * IN + k]);
    }
    __syncthreads();
    int o = t % OUTP;
    int g = t / OUTP;
    double acc[ROWS];
    double bias = (o < OUT) ? (double)qb[o] : 0.0;
    #pragma unroll
    for (int r = 0; r < ROWS; ++r) acc[r] = bias;
    #pragma unroll 4
    for (int k = 0; k < IN; ++k) {
        double w = (double)Wt[k * OUTP + o];   // coalesced, L2-resident
        #pragma unroll
        for (int r = 0; r < ROWS; ++r)
            acc[r] = fma(sx[g * ROWS + r][k], w, acc[r]);  // LDS broadcast reads
    }
    if (o < OUT) {
        #pragma unroll
        for (int r = 0; r < ROWS; ++r) {
            double q = fq_d(acc[r]);
            if (do_relu && q < 0.0) q = 0.0;
            size_t b = (size_t)(b0 + g * ROWS + r);
            if (outf) outf[b * OUT + o] = (float)q;
            else      outb[b * OUT + o] = __float2bfloat16((float)q);
        }
    }
}

// ---------------------------------------------------------------------------
extern "C" void kernel_launch(void* const* d_in, const int* in_sizes, int n_in,
                              void* d_out, int out_size, void* d_ws, size_t ws_size,
                              hipStream_t stream) {
    const float* x   = (const float*)d_in[0];
    const float* w1  = (const float*)d_in[1];
    const float* g1  = (const float*)d_in[2];
    const float* be1 = (const float*)d_in[3];
    const float* w2  = (const float*)d_in[4];
    const float* g2  = (const float*)d_in[5];
    const float* be2 = (const float*)d_in[6];
    const float* fw1 = (const float*)d_in[7];
    const float* fb1 = (const float*)d_in[8];
    const float* fw2 = (const float*)d_in[9];
    const float* fb2 = (const float*)d_in[10];
    const float* fw3 = (const float*)d_in[11];
    const float* fb3 = (const float*)d_in[12];

    char* ws = (char*)d_ws;
    double* stats1 = (double*)(ws + 0);      // 12 dbl
    double* mr1    = (double*)(ws + 256);    // 12 dbl
    double* stats2 = (double*)(ws + 512);    // 32 dbl
    double* mr2    = (double*)(ws + 768);    // 32 dbl
    float* qw1  = (float*)(ws + 1024);       // 150
    float* qw2  = (float*)(ws + 2048);       // 2400 (ends 11648)
    float* qfb1 = (float*)(ws + 12288);      // 120
    float* qfb2 = (float*)(ws + 12800);      // 84
    float* qfb3 = (float*)(ws + 13184);      // 10
    float* Wt1  = (float*)(ws + 16384);      // 400*128 (ends 221184)
    float* Wt2  = (float*)(ws + 221184);     // 120*128 (ends 282624)
    float* Wt3  = (float*)(ws + 282624);     // 84*16   (ends 288000)
    // big buffers (aliased by liveness)
    __hip_bfloat16* bufA = (__hip_bfloat16*)(ws + 294912);    // c1 [B,6,28,28] then c2 [B,16,10,10]
    __hip_bfloat16* bufB = (__hip_bfloat16*)(ws + 77365248);  // p1 [B,6,14,14] then p2 [B,400]
    __hip_bfloat16* bufC = (__hip_bfloat16*)(ws + 294912);    // a1 [B,120] (aliases dead bufA)
    __hip_bfloat16* bufD = (__hip_bfloat16*)(ws + 294912 + 2097152); // a2 [B,84]

    hipMemsetAsync(ws, 0, 1024, stream);

    kprep<<<(PREP_TOTAL + 255) / 256, 256, 0, stream>>>(
        w1, w2, fb1, fb2, fb3, fw1, fw2, fw3,
        qw1, qw2, qfb1, qfb2, qfb3, Wt1, Wt2, Wt3);

    // conv1 + fq -> bufA [B,6,28,28]   (3 images per block, 2x7 tiles)
    kconv1<<<(BATCH + 2) / 3, 256, 0, stream>>>(x, qw1, bufA, BATCH);
    kstats<<<dim3(6, 256), 256, 0, stream>>>(bufA, stats1, 6, 784, BATCH);
    kfinal<<<1, 32, 0, stream>>>(stats1, mr1, 6, (double)BATCH * 784.0);
    {
        int total = BATCH * 6 * 14 * 14;
        kbnpool<<<(total + 255) / 256, 256, 0, stream>>>(bufA, mr1, g1, be1, bufB, 6, 28, 28, total);
    }
    // conv2 + fq -> bufA [B,16,10,10]  (2 images per block, 320 threads)
    kconv2<<<BATCH / 2, 320, 0, stream>>>(bufB, qw2, bufA);
    kstats<<<dim3(16, 256), 256, 0, stream>>>(bufA, stats2, 16, 100, BATCH);
    kfinal<<<1, 32, 0, stream>>>(stats2, mr2, 16, (double)BATCH * 100.0);
    {
        int total = BATCH * 16 * 5 * 5;
        kbnpool<<<(total + 255) / 256, 256, 0, stream>>>(bufA, mr2, g2, be2, bufB, 16, 10, 10, total);
    }
    // fc1 (+relu): [B,400] -> [B,120]
    kfc<400, 120, 128, 8><<<BATCH / 16, 256, 0, stream>>>(bufB, Wt1, qfb1, bufC, (float*)nullptr, 1);
    // fc2 (+relu): [B,120] -> [B,84]
    kfc<120, 84, 128, 8><<<BATCH / 16, 256, 0, stream>>>(bufC, Wt2, qfb2, bufD, (float*)nullptr, 1);
    // fc3: [B,84] -> [B,10] float out
    kfc<84, 10, 16, 1><<<BATCH / 16, 256, 0, stream>>>(bufD, Wt3, qfb3, (__hip_bfloat16*)nullptr, (float*)d_out, 0);
}

// Round 7
// 481.524 us; speedup vs baseline: 2.3910x; 1.1716x over previous
//
#include <hip/hip_runtime.h>
#include <hip/hip_bf16.h>

// ---------------------------------------------------------------------------
// QLenet forward, exact-math strategy (round-0 notes):
//   All fq() outputs are e5m2 grid values (<=3 significant bits). Products of
//   two grid values have <=6-bit mantissas; dot sums (<=400 terms, bounded
//   exponent span) are EXACT in f64 -> order-independent -> matches float64
//   numpy reference. Intermediates stored as bf16 (exact for grid values).
//   Grid values are also EXACT in f32 -> LDS tiles hold f32, cvt to f64 at
//   use (1 cvt amortized over ~10 FMAs). Accumulation stays f64.
// Round 6 -> 7:
//   * kconv2: 2x10 row-pair tile with rotated-w row reuse + f32 LDS
//     (reads/FMA 0.38 -> 0.22, bytes/read halved) -> LDS-BW ~76 -> ~22us,
//     FMA floor 50us. 4 img/block, 320 threads = 320 tasks exactly.
//   * kconv1: x tile f32 (stride 33 kept), removed junk placeholder stores.
//   * BN stats fused into conv epilogues (shared f64 atomics -> 32-binned
//     global f64 atomics); kstats passes deleted. kfinal sums bins.
// ---------------------------------------------------------------------------

#define BATCH 8192

// fq: round to FP(e5m2) nearest-even, subnormal granule 2^-16, clip +-57344.
// Normal path (|x| >= 2^-14): integer round-to-nearest-even of the f64
// mantissa to 2 bits; carry propagates into the exponent automatically.
__device__ __forceinline__ double fq_d(double x) {
    long long b = __double_as_longlong(x);
    long long ab = b & 0x7fffffffffffffffLL;
    if (ab == 0) return x;                       // +-0 preserved (ref: where(ax>0,...))
    double q;
    if (ab >= 0x3F10000000000000LL) {            // |x| >= 2^-14
        long long r = b + 0x0001FFFFFFFFFFFFLL + ((b >> 50) & 1LL);
        r &= 0xFFFC000000000000LL;               // clear low 50 mantissa bits
        q = __longlong_as_double(r);
        q = fmin(fmax(q, -57344.0), 57344.0);
    } else {                                     // subnormal grid: 2^-16
        q = rint(x * 65536.0) * 1.52587890625e-05;
    }
    return q;
}

__device__ __forceinline__ unsigned short bfbits(double q) {
    __hip_bfloat16 h = __float2bfloat16((float)q);   // exact for grid values
    return *(unsigned short*)&h;
}

// ---------------- merged prep: quantize conv weights, fc biases; transpose+
// quantize fc weights (padded). Flat index over all segments. ----------------
__global__ void kprep(const float* __restrict__ w1, const float* __restrict__ w2,
                      const float* __restrict__ fb1, const float* __restrict__ fb2,
                      const float* __restrict__ fb3, const float* __restrict__ fw1,
                      const float* __restrict__ fw2, const float* __restrict__ fw3,
                      float* __restrict__ qw1, float* __restrict__ qw2,
                      float* __restrict__ qfb1, float* __restrict__ qfb2,
                      float* __restrict__ qfb3, float* __restrict__ Wt1,
                      float* __restrict__ Wt2, float* __restrict__ Wt3) {
    int i = blockIdx.x * 256 + threadIdx.x;
    if (i < 150) { qw1[i] = (float)fq_d((double)w1[i]); return; }
    i -= 150;
    if (i < 2400) { qw2[i] = (float)fq_d((double)w2[i]); return; }
    i -= 2400;
    if (i < 120) { qfb1[i] = (float)fq_d((double)fb1[i]); return; }
    i -= 120;
    if (i < 84) { qfb2[i] = (float)fq_d((double)fb2[i]); return; }
    i -= 84;
    if (i < 10) { qfb3[i] = (float)fq_d((double)fb3[i]); return; }
    i -= 10;
    if (i < 51200) { int k = i / 128, o = i % 128;
        Wt1[i] = (o < 120) ? (float)fq_d((double)fw1[o * 400 + k]) : 0.0f; return; }
    i -= 51200;
    if (i < 15360) { int k = i / 128, o = i % 128;
        Wt2[i] = (o < 84) ? (float)fq_d((double)fw2[o * 120 + k]) : 0.0f; return; }
    i -= 15360;
    if (i < 1344) { int k = i / 16, o = i % 16;
        Wt3[i] = (o < 10) ? (float)fq_d((double)fw3[o * 84 + k]) : 0.0f; return; }
}
#define PREP_TOTAL (150 + 2400 + 120 + 84 + 10 + 51200 + 15360 + 1344)

// ---------------- conv1 + fq + fused BN stats ----------------
// [B,1,32,32] -> [B,6,28,28]. 3 images/block; task = 2x7 output tile with
// rotated-w row reuse. x tile f32, stride 33. Stats: per-task (s,s2) ->
// shared f64 atomics per channel -> 32-binned global atomics.
__global__ __launch_bounds__(256) void kconv1(const float* __restrict__ x,
        const float* __restrict__ qw, __hip_bfloat16* __restrict__ c1,
        int nimg_total, double* __restrict__ st1) {
    __shared__ float sxf[3 * 1056];   // 3 x (32 rows x 33) f32
    __shared__ double swd[152];
    __shared__ double sred[6][2];
    int t = threadIdx.x;
    int b0 = blockIdx.x * 3;
    int nimg = nimg_total - b0; if (nimg > 3) nimg = 3;
    for (int i = t; i < nimg * 1024; i += 256) {
        int img = i >> 10, idx = i & 1023;
        sxf[img * 1056 + (idx >> 5) * 33 + (idx & 31)] =
            (float)fq_d((double)x[(size_t)(b0 + img) * 1024 + idx]);
    }
    if (t < 150) swd[t] = (double)qw[t];
    if (t >= 192 && t < 204) ((double*)sred)[t - 192] = 0.0;
    __syncthreads();
    int ntask = nimg * 336;           // 6 co x 14 rowpairs x 4 colchunks
    for (int task = t; task < ntask; task += 256) {
        int img = task / 336; int rr = task % 336;
        int co = rr / 56; int rem = rr % 56;
        int i0 = (rem >> 2) * 2;      // 0,2,...,26
        int j0 = (rem & 3) * 7;       // 0,7,14,21
        const float* xb = &sxf[img * 1056];
        const double* wp = &swd[co * 25];
        double a0[7], a1[7];
        #pragma unroll
        for (int j = 0; j < 7; ++j) { a0[j] = 0.0; a1[j] = 0.0; }
        double wr[5], wq[5];
        #pragma unroll
        for (int u = 0; u < 6; ++u) {
            const float* xr = &xb[(i0 + u) * 33 + j0];
            double xv[11];
            #pragma unroll
            for (int k = 0; k < 11; ++k) xv[k] = (double)xr[k];
            if (u < 5) {
                #pragma unroll
                for (int tt = 0; tt < 5; ++tt) wr[tt] = wp[u * 5 + tt];
                #pragma unroll
                for (int j = 0; j < 7; ++j)
                    a0[j] = fma(xv[j], wr[0], fma(xv[j+1], wr[1], fma(xv[j+2], wr[2],
                            fma(xv[j+3], wr[3], fma(xv[j+4], wr[4], a0[j])))));
            }
            if (u >= 1) {
                #pragma unroll
                for (int j = 0; j < 7; ++j)
                    a1[j] = fma(xv[j], wq[0], fma(xv[j+1], wq[1], fma(xv[j+2], wq[2],
                            fma(xv[j+3], wq[3], fma(xv[j+4], wq[4], a1[j])))));
            }
            #pragma unroll
            for (int tt = 0; tt < 5; ++tt) wq[tt] = wr[tt];   // SSA rotate
        }
        size_t base = ((size_t)(b0 + img) * 6 + co) * 784 + (size_t)i0 * 28 + j0;
        double s = 0.0, s2 = 0.0;
        #pragma unroll
        for (int j = 0; j < 7; ++j) {
            double q0 = fq_d(a0[j]), q1 = fq_d(a1[j]);
            ((unsigned short*)c1)[base + j]      = bfbits(q0);
            ((unsigned short*)c1)[base + 28 + j] = bfbits(q1);
            s += q0 + q1; s2 += q0 * q0 + q1 * q1;
        }
        atomicAdd(&sred[co][0], s);
        atomicAdd(&sred[co][1], s2);
    }
    __syncthreads();
    if (t < 12) atomicAdd(&st1[t * 32 + (blockIdx.x & 31)], ((double*)sred)[t]);
}

// ---------------- finalize BN from 32-binned stats: m, rsqrt(v+eps) --------
__global__ void kfinal(const double* __restrict__ st, double* __restrict__ mr,
                       int C, double N) {
    int c = threadIdx.x;
    if (c < C) {
        double s = 0.0, s2 = 0.0;
        for (int b = 0; b < 32; ++b) { s += st[c * 64 + b]; s2 += st[c * 64 + 32 + b]; }
        double m = s / N;
        double v = s2 / N - m * m;
        mr[2 * c] = m;
        mr[2 * c + 1] = 1.0 / sqrt(v + 1e-5);
    }
}

// ---------------- bn + fq + relu + 2x2 maxpool ----------------
__global__ __launch_bounds__(256) void kbnpool(const __hip_bfloat16* __restrict__ cin,
        const double* __restrict__ mr, const float* __restrict__ g, const float* __restrict__ be,
        __hip_bfloat16* __restrict__ pout, int C, int H, int W, int total) {
    int idx = blockIdx.x * 256 + threadIdx.x;
    if (idx >= total) return;
    int Ho = H >> 1, Wo = W >> 1;
    int wo = idx % Wo; int t1 = idx / Wo;
    int ho = t1 % Ho;  int t2 = t1 / Ho;
    int c = t2 % C;    int b = t2 / C;
    double m = mr[2 * c], r = mr[2 * c + 1];
    double gg = (double)g[c], bb = (double)be[c];
    const __hip_bfloat16* base = cin + (((size_t)b * C + c) * H + 2 * ho) * W + 2 * wo;
    float best = 0.0f;   // relu(fq(v)) then max == max(0, fq(v)...)
    #pragma unroll
    for (int dy = 0; dy < 2; ++dy) {
        #pragma unroll
        for (int dx = 0; dx < 2; ++dx) {
            double v = (double)__bfloat162float(base[dy * W + dx]);
            double q = fq_d(((v - m) * r) * gg + bb);
            best = fmaxf(best, (float)q);
        }
    }
    pout[idx] = __float2bfloat16(best);
}

// ---------------- conv2 + fq + fused BN stats ----------------
// [B,6,14,14] -> [B,16,10,10]. 4 images/block, 320 threads; task = 2x10
// row-pair tile with rotated-w row reuse. x,w in LDS as f32 (exact), f64 acc.
__global__ __launch_bounds__(320) void kconv2(const __hip_bfloat16* __restrict__ p1,
        const float* __restrict__ qw, __hip_bfloat16* __restrict__ c2,
        double* __restrict__ st2) {
    __shared__ float sxf[4704];    // 4 x [6][14][14]
    __shared__ float swf[2400];    // [16][6][5][5]
    __shared__ double sred[16][2];
    int t = threadIdx.x;
    int b0 = blockIdx.x * 4;
    for (int i = t; i < 4704; i += 320) sxf[i] = __bfloat162float(p1[(size_t)b0 * 1176 + i]);
    for (int i = t; i < 2400; i += 320) swf[i] = qw[i];
    if (t < 32) ((double*)sred)[t] = 0.0;
    __syncthreads();
    int img = t / 80, r = t % 80;
    int co = r / 5, i0 = (r % 5) * 2;
    const float* xb = &sxf[img * 1176];
    const float* wb = &swf[co * 150];
    double a0[10], a1[10];
    #pragma unroll
    for (int j = 0; j < 10; ++j) { a0[j] = 0.0; a1[j] = 0.0; }
    double wr[5], wq[5];
    for (int ci = 0; ci < 6; ++ci) {
        #pragma unroll
        for (int u = 0; u < 6; ++u) {
            const float* xr = &xb[ci * 196 + (i0 + u) * 14];
            double xv[14];
            #pragma unroll
            for (int k = 0; k < 14; ++k) xv[k] = (double)xr[k];
            if (u < 5) {
                #pragma unroll
                for (int tt = 0; tt < 5; ++tt) wr[tt] = (double)wb[ci * 25 + u * 5 + tt];
                #pragma unroll
                for (int j = 0; j < 10; ++j)
                    a0[j] = fma(xv[j], wr[0], fma(xv[j+1], wr[1], fma(xv[j+2], wr[2],
                            fma(xv[j+3], wr[3], fma(xv[j+4], wr[4], a0[j])))));
            }
            if (u >= 1) {
                #pragma unroll
                for (int j = 0; j < 10; ++j)
                    a1[j] = fma(xv[j], wq[0], fma(xv[j+1], wq[1], fma(xv[j+2], wq[2],
                            fma(xv[j+3], wq[3], fma(xv[j+4], wq[4], a1[j])))));
            }
            #pragma unroll
            for (int tt = 0; tt < 5; ++tt) wq[tt] = wr[tt];   // SSA rotate
        }
    }
    size_t base = ((size_t)(b0 + img) * 16 + co) * 100 + (size_t)i0 * 10;
    double s = 0.0, s2 = 0.0;
    #pragma unroll
    for (int j = 0; j < 10; ++j) {
        double q0 = fq_d(a0[j]), q1 = fq_d(a1[j]);
        ((unsigned short*)c2)[base + j]      = bfbits(q0);
        ((unsigned short*)c2)[base + 10 + j] = bfbits(q1);
        s += q0 + q1; s2 += q0 * q0 + q1 * q1;
    }
    atomicAdd(&sred[co][0], s);
    atomicAdd(&sred[co][1], s2);
    __syncthreads();
    if (t < 32) atomicAdd(&st2[t * 32 + (blockIdx.x & 31)], ((double*)sred)[t]);
}

// ---------------- tiled FC: out = [relu?] fq( X @ Wt + qb ) ----------------
template<int IN, int OUT, int OUTP, int ROWS>
__global__ __launch_bounds__(256) void kfc(const __hip_bfloat16* __restrict__ X,
        const float* __restrict__ Wt, const float* __restrict__ qb,
        __hip_bfloat16* __restrict__ outb, float* __restrict__ outf, int do_relu) {
    constexpr int GROUPS = 256 / OUTP;
    constexpr int BT = ROWS * GROUPS;
    __shared__ double sx[BT][IN];
    int t = threadIdx.x;
    int b0 = blockIdx.x * BT;
    for (int i = t; i < BT * IN; i += 256) {
        int r = i / IN, k = i % IN;
        sx[r][k] = (double)__bfloat162float(X[(size_t)(b0 + r) * IN + k]);
    }
    __syncthreads();
    int o = t % OUTP;
    int g = t / OUTP;
    double acc[ROWS];
    double bias = (o < OUT) ? (double)qb[o] : 0.0;
    #pragma unroll
    for (int r = 0; r < ROWS; ++r) acc[r] = bias;
    #pragma unroll 4
    for (int k = 0; k < IN; ++k) {
        double w = (double)Wt[k * OUTP + o];   // coalesced, L2-resident
        #pragma unroll
        for (int r = 0; r < ROWS; ++r)
            acc[r] = fma(sx[g * ROWS + r][k], w, acc[r]);  // LDS broadcast reads
    }
    if (o < OUT) {
        #pragma unroll
        for (int r = 0; r < ROWS; ++r) {
            double q = fq_d(acc[r]);
            if (do_relu && q < 0.0) q = 0.0;
            size_t b = (size_t)(b0 + g * ROWS + r);
            if (outf) outf[b * OUT + o] = (float)q;
            else      outb[b * OUT + o] = __float2bfloat16((float)q);
        }
    }
}

// ---------------------------------------------------------------------------
extern "C" void kernel_launch(void* const* d_in, const int* in_sizes, int n_in,
                              void* d_out, int out_size, void* d_ws, size_t ws_size,
                              hipStream_t stream) {
    const float* x   = (const float*)d_in[0];
    const float* w1  = (const float*)d_in[1];
    const float* g1  = (const float*)d_in[2];
    const float* be1 = (const float*)d_in[3];
    const float* w2  = (const float*)d_in[4];
    const float* g2  = (const float*)d_in[5];
    const float* be2 = (const float*)d_in[6];
    const float* fw1 = (const float*)d_in[7];
    const float* fb1 = (const float*)d_in[8];
    const float* fw2 = (const float*)d_in[9];
    const float* fb2 = (const float*)d_in[10];
    const float* fw3 = (const float*)d_in[11];
    const float* fb3 = (const float*)d_in[12];

    char* ws = (char*)d_ws;
    double* stats1 = (double*)(ws + 0);      // [6][2][32] dbl = 3072 B
    double* stats2 = (double*)(ws + 3072);   // [16][2][32] dbl = 8192 B (ends 11264)
    double* mr1    = (double*)(ws + 11264);  // 12 dbl
    double* mr2    = (double*)(ws + 11392);  // 32 dbl
    float* qw1  = (float*)(ws + 12288);      // 150
    float* qw2  = (float*)(ws + 13312);      // 2400 (ends 22912)
    float* qfb1 = (float*)(ws + 23040);      // 120
    float* qfb2 = (float*)(ws + 23552);      // 84
    float* qfb3 = (float*)(ws + 24064);      // 10
    float* Wt1  = (float*)(ws + 24576);      // 400*128 (ends 229376)
    float* Wt2  = (float*)(ws + 229376);     // 120*128 (ends 290816)
    float* Wt3  = (float*)(ws + 290816);     // 84*16   (ends 296192)
    // big buffers (aliased by liveness)
    __hip_bfloat16* bufA = (__hip_bfloat16*)(ws + 303104);    // c1 [B,6,28,28] then c2 [B,16,10,10]
    __hip_bfloat16* bufB = (__hip_bfloat16*)(ws + 77373440);  // p1 [B,6,14,14] then p2 [B,400]
    __hip_bfloat16* bufC = (__hip_bfloat16*)(ws + 303104);    // a1 [B,120] (aliases dead bufA)
    __hip_bfloat16* bufD = (__hip_bfloat16*)(ws + 303104 + 2097152); // a2 [B,84]

    // zero the binned BN accumulators
    hipMemsetAsync(ws, 0, 11264, stream);

    kprep<<<(PREP_TOTAL + 255) / 256, 256, 0, stream>>>(
        w1, w2, fb1, fb2, fb3, fw1, fw2, fw3,
        qw1, qw2, qfb1, qfb2, qfb3, Wt1, Wt2, Wt3);

    // conv1 + fq + stats -> bufA [B,6,28,28]
    kconv1<<<(BATCH + 2) / 3, 256, 0, stream>>>(x, qw1, bufA, BATCH, stats1);
    kfinal<<<1, 32, 0, stream>>>(stats1, mr1, 6, (double)BATCH * 784.0);
    {
        int total = BATCH * 6 * 14 * 14;
        kbnpool<<<(total + 255) / 256, 256, 0, stream>>>(bufA, mr1, g1, be1, bufB, 6, 28, 28, total);
    }
    // conv2 + fq + stats -> bufA [B,16,10,10]  (4 images/block, 320 threads)
    kconv2<<<BATCH / 4, 320, 0, stream>>>(bufB, qw2, bufA, stats2);
    kfinal<<<1, 32, 0, stream>>>(stats2, mr2, 16, (double)BATCH * 100.0);
    {
        int total = BATCH * 16 * 5 * 5;
        kbnpool<<<(total + 255) / 256, 256, 0, stream>>>(bufA, mr2, g2, be2, bufB, 16, 10, 10, total);
    }
    // fc1 (+relu): [B,400] -> [B,120]
    kfc<400, 120, 128, 8><<<BATCH / 16, 256, 0, stream>>>(bufB, Wt1, qfb1, bufC, (float*)nullptr, 1);
    // fc2 (+relu): [B,120] -> [B,84]
    kfc<120, 84, 128, 8><<<BATCH / 16, 256, 0, stream>>>(bufC, Wt2, qfb2, bufD, (float*)nullptr, 1);
    // fc3: [B,84] -> [B,10] float out
    kfc<84, 10, 16, 1><<<BATCH / 16, 256, 0, stream>>>(bufD, Wt3, qfb3, (__hip_bfloat16*)nullptr, (float*)d_out, 0);
}